// Round 5
// baseline (304.256 us; speedup 1.0000x reference)
//
#include <hip/hip_runtime.h>
#include <hip/hip_bf16.h>

#define BB 2
#define TT 2048
#define DMM 1024
#define HH 16
#define HDD 64

typedef __attribute__((ext_vector_type(8))) short bf16x8;
typedef __attribute__((ext_vector_type(4))) short short4v;
typedef __attribute__((ext_vector_type(4))) float f32x4;

static __device__ __forceinline__ short f2bf(float f) {
    __hip_bfloat16 h = __float2bfloat16(f);
    return *reinterpret_cast<short*>(&h);
}

// ---- hidden f32 -> bf16 (4 elems/thread) ----
__global__ void cvt_hidden(const float* __restrict__ x, short* __restrict__ y) {
    int i = blockIdx.x * 256 + threadIdx.x;          // 1M threads, 4M elems
    float4 v = reinterpret_cast<const float4*>(x)[i];
    short4v o;
    o[0] = f2bf(v.x); o[1] = f2bf(v.y); o[2] = f2bf(v.z); o[3] = f2bf(v.w);
    reinterpret_cast<short4v*>(y)[i] = o;
}

// ---- W_eff = W + 2.0 * B@A  (or plain W), cast bf16 ----
__global__ void prep_w(const float* __restrict__ W, const float* __restrict__ A,
                       const float* __restrict__ Bm, short* __restrict__ outp, int lora) {
    int idx = blockIdx.x * 256 + threadIdx.x;        // 1M elems
    int n = idx >> 10, k = idx & 1023;
    float v = W[idx];
    if (lora) {
        float s = 0.f;
#pragma unroll
        for (int r = 0; r < 8; ++r) s += Bm[n * 8 + r] * A[r * 1024 + k];
        v += 2.0f * s;
    }
    outp[idx] = f2bf(v);
}

// ---- projection GEMM: C[m,n] = X[m,:] . W[n,:]  (both row-major, K contiguous) ----
// z = 0: Q (scale 0.125, layout [b][h][t][d]); z=1: K (same layout); z=2: V -> [b][h][d][t]
__global__ __launch_bounds__(256) void proj_gemm(
        const short* __restrict__ Xbf,
        const short* __restrict__ Wq, const short* __restrict__ Wk, const short* __restrict__ Wv,
        const float* __restrict__ bq, const float* __restrict__ bk, const float* __restrict__ bv,
        short* __restrict__ Qb, short* __restrict__ Kb, short* __restrict__ Vtb) {
    __shared__ __align__(16) char As[128 * 128];     // 128 rows x 64 bf16 (128B), swizzled
    __shared__ __align__(16) char Bs[128 * 128];

    const int mode = blockIdx.z;
    const short* Wbf = (mode == 0) ? Wq : (mode == 1) ? Wk : Wv;
    const float* bias = (mode == 0) ? bq : (mode == 1) ? bk : bv;
    short* outp = (mode == 0) ? Qb : (mode == 1) ? Kb : Vtb;
    const float scale = (mode == 0) ? 0.125f : 1.0f;  // HD^-0.5 folded into Q

    const int tid = threadIdx.x;
    const int wave = tid >> 6, lane = tid & 63;
    const int l15 = lane & 15, l4 = lane >> 4;
    const int m0 = blockIdx.y * 128, n0 = blockIdx.x * 128;
    const int wm = (wave >> 1) * 64, wn = (wave & 1) * 64;

    const int srow = tid >> 1;            // staging row 0..127
    const int scc = (tid & 1) * 4;        // 16B-chunk base (of 8 per row)

    f32x4 acc[4][4] = {};

    for (int k0 = 0; k0 < 1024; k0 += 64) {
        __syncthreads();
#pragma unroll
        for (int c = 0; c < 4; ++c) {
            int cc = scc + c;
            uint4 va = *reinterpret_cast<const uint4*>(Xbf + (m0 + srow) * 1024 + k0 + cc * 8);
            *reinterpret_cast<uint4*>(As + ((srow * 128 + cc * 16) ^ ((srow & 7) << 4))) = va;
            uint4 vb = *reinterpret_cast<const uint4*>(Wbf + (n0 + srow) * 1024 + k0 + cc * 8);
            *reinterpret_cast<uint4*>(Bs + ((srow * 128 + cc * 16) ^ ((srow & 7) << 4))) = vb;
        }
        __syncthreads();
#pragma unroll
        for (int kk = 0; kk < 2; ++kk) {
            const int colb = kk * 64 + l4 * 16;
            bf16x8 af[4], bfr[4];
#pragma unroll
            for (int mi = 0; mi < 4; ++mi) {
                int rowa = wm + mi * 16 + l15;
                af[mi] = *reinterpret_cast<const bf16x8*>(As + ((rowa * 128 + colb) ^ ((rowa & 7) << 4)));
                int rowb = wn + mi * 16 + l15;
                bfr[mi] = *reinterpret_cast<const bf16x8*>(Bs + ((rowb * 128 + colb) ^ ((rowb & 7) << 4)));
            }
#pragma unroll
            for (int mi = 0; mi < 4; ++mi)
#pragma unroll
                for (int ni = 0; ni < 4; ++ni)
                    acc[mi][ni] = __builtin_amdgcn_mfma_f32_16x16x32_bf16(af[mi], bfr[ni], acc[mi][ni], 0, 0, 0);
        }
    }

    // epilogue: C row = (l>>4)*4 + r, col = l&15
#pragma unroll
    for (int mi = 0; mi < 4; ++mi)
#pragma unroll
        for (int ni = 0; ni < 4; ++ni) {
            int gn = n0 + wn + ni * 16 + l15;
            float bv = bias[gn];
            int h = gn >> 6, d = gn & 63;
#pragma unroll
            for (int r = 0; r < 4; ++r) {
                int gm = m0 + wm + mi * 16 + l4 * 4 + r;
                int b = gm >> 11, t = gm & 2047;
                float v = (acc[mi][ni][r] + bv) * scale;
                int off;
                if (mode == 2) off = ((b * 16 + h) * 64 + d) * 2048 + t;     // V transposed
                else           off = ((b * 16 + h) * 2048 + t) * 64 + d;
                outp[off] = f2bf(v);
            }
        }
}

// ---- flash attention v3: split-KV, all-resident grid ----
// 1024 blocks x 4 waves. Block handles 2 q-tile pairs (2j+pg, 127-(2j+pg)).
// Wave (pg, hf) does kv-half hf of both tiles of pair pg -> uniform work (~16.5 KVBLK iters).
// Halves merged lane-aligned through LDS (identical MFMA fragment layouts).

#define LOADK(dst, kvb_) do {                                                        \
    int _kb = (kvb_);                                                                \
    _Pragma("unroll")                                                                \
    for (int _sl = 0; _sl < 4; ++_sl) {                                              \
        dst[_sl][0] = *reinterpret_cast<const bf16x8*>(Kp + (_kb + _sl*16 + l15)*64 + l4*8);      \
        dst[_sl][1] = *reinterpret_cast<const bf16x8*>(Kp + (_kb + _sl*16 + l15)*64 + 32 + l4*8); \
    }                                                                                \
} while (0)

#define PROC(CUR, NXT, KT) do {                                                      \
    const int kvb_ = (KT) << 6;                                                      \
    LOADK(NXT, kvb_ + 64);                                                           \
    bf16x8 vf[4][2];                                                                 \
    _Pragma("unroll")                                                                \
    for (int dt = 0; dt < 4; ++dt) {                                                 \
        vf[dt][0] = *reinterpret_cast<const bf16x8*>(Vp + (dt*16 + l15)*2048 + kvb_ + l4*8);      \
        vf[dt][1] = *reinterpret_cast<const bf16x8*>(Vp + (dt*16 + l15)*2048 + kvb_ + 32 + l4*8); \
    }                                                                                \
    float mvs[4];                                                                    \
    _Pragma("unroll")                                                                \
    for (int sl = 0; sl < 4; ++sl) mvs[sl] = mp[kvb_ + sl*16 + l15];                 \
    f32x4 ss[4] = {};                                                                \
    _Pragma("unroll")                                                                \
    for (int sl = 0; sl < 4; ++sl) {                                                 \
        ss[sl] = __builtin_amdgcn_mfma_f32_16x16x32_bf16(qf0, CUR[sl][0], ss[sl], 0, 0, 0); \
        ss[sl] = __builtin_amdgcn_mfma_f32_16x16x32_bf16(qf1, CUR[sl][1], ss[sl], 0, 0, 0); \
    }                                                                                \
    float pr[4][4];                                                                  \
    if (kvb_ + 63 > qbase) {                                                         \
        _Pragma("unroll")                                                            \
        for (int sl = 0; sl < 4; ++sl)                                               \
            _Pragma("unroll")                                                        \
            for (int r = 0; r < 4; ++r) {                                            \
                float v = ss[sl][r] + mvs[sl];                                       \
                if (kvb_ + sl*16 + l15 > qbase + l4*4 + r) v = -1e30f;               \
                pr[sl][r] = v;                                                       \
            }                                                                        \
    } else {                                                                         \
        _Pragma("unroll")                                                            \
        for (int sl = 0; sl < 4; ++sl)                                               \
            _Pragma("unroll")                                                        \
            for (int r = 0; r < 4; ++r) pr[sl][r] = ss[sl][r] + mvs[sl];             \
    }                                                                                \
    float rmax[4];                                                                   \
    _Pragma("unroll")                                                                \
    for (int r = 0; r < 4; ++r) {                                                    \
        rmax[r] = fmaxf(fmaxf(pr[0][r], pr[1][r]), fmaxf(pr[2][r], pr[3][r]));       \
        _Pragma("unroll")                                                            \
        for (int d = 1; d < 16; d <<= 1)                                             \
            rmax[r] = fmaxf(rmax[r], __shfl_xor(rmax[r], d, 16));                    \
    }                                                                                \
    float g = fmaxf(fmaxf(rmax[0]-mrow[0], rmax[1]-mrow[1]),                         \
                    fmaxf(rmax[2]-mrow[2], rmax[3]-mrow[3]));                        \
    if (!__all(g <= 8.0f)) {                                                         \
        _Pragma("unroll")                                                            \
        for (int r = 0; r < 4; ++r) {                                                \
            float mn = fmaxf(mrow[r], rmax[r]);                                      \
            float al = __expf(mrow[r] - mn);                                         \
            mrow[r] = mn; lrow[r] *= al;                                             \
            _Pragma("unroll")                                                        \
            for (int dt = 0; dt < 4; ++dt) O[dt][r] *= al;                           \
        }                                                                            \
    }                                                                                \
    _Pragma("unroll")                                                                \
    for (int sl = 0; sl < 4; ++sl)                                                   \
        _Pragma("unroll")                                                            \
        for (int r = 0; r < 4; ++r) pr[sl][r] = __expf(pr[sl][r] - mrow[r]);         \
    _Pragma("unroll")                                                                \
    for (int r = 0; r < 4; ++r) {                                                    \
        float ps = (pr[0][r] + pr[1][r]) + (pr[2][r] + pr[3][r]);                    \
        _Pragma("unroll")                                                            \
        for (int d = 1; d < 16; d <<= 1) ps += __shfl_xor(ps, d, 16);                \
        lrow[r] += ps;                                                               \
    }                                                                                \
    _Pragma("unroll")                                                                \
    for (int sl = 0; sl < 4; ++sl)                                                   \
        _Pragma("unroll")                                                            \
        for (int r = 0; r < 4; ++r)                                                  \
            pbw[(l4*4 + r)*72 + sl*16 + l15] = f2bf(pr[sl][r]);                      \
    asm volatile("s_waitcnt lgkmcnt(0)" ::: "memory");                               \
    bf16x8 pf0 = *reinterpret_cast<const bf16x8*>(pbw + l15*72 + l4*8);              \
    bf16x8 pf1 = *reinterpret_cast<const bf16x8*>(pbw + l15*72 + 32 + l4*8);         \
    _Pragma("unroll")                                                                \
    for (int dt = 0; dt < 4; ++dt) {                                                 \
        O[dt] = __builtin_amdgcn_mfma_f32_16x16x32_bf16(pf0, vf[dt][0], O[dt], 0, 0, 0); \
        O[dt] = __builtin_amdgcn_mfma_f32_16x16x32_bf16(pf1, vf[dt][1], O[dt], 0, 0, 0); \
    }                                                                                \
} while (0)

// One q-tile job over kv tiles [kt0, kt1), then cross-wave merge through LDS.
// hf==1 wave writes partials; hf==0 wave merges and writes global output.
#define JOB(QT, PHASE) do {                                                          \
    const int qbase = (QT) << 4;                                                     \
    const int nkt = (qbase + 79) >> 6;                                               \
    const int hb = (nkt + 1) >> 1;                                                   \
    const int kt0 = hf ? hb : 0;                                                     \
    const int kt1 = hf ? nkt : hb;                                                   \
    f32x4 O[4] = {};                                                                 \
    float mrow[4] = {-1e30f, -1e30f, -1e30f, -1e30f};                                \
    float lrow[4] = {0.f, 0.f, 0.f, 0.f};                                            \
    if (kt0 < kt1) {                                                                 \
        bf16x8 qf0 = *reinterpret_cast<const bf16x8*>(Qp + (qbase + l15)*64 + l4*8);      \
        bf16x8 qf1 = *reinterpret_cast<const bf16x8*>(Qp + (qbase + l15)*64 + 32 + l4*8); \
        bf16x8 kfA[4][2], kfB[4][2];                                                 \
        LOADK(kfA, kt0 << 6);                                                        \
        int kt = kt0;                                                                \
        while (1) {                                                                  \
            PROC(kfA, kfB, kt);                                                      \
            if (++kt >= kt1) break;                                                  \
            PROC(kfB, kfA, kt);                                                      \
            if (++kt >= kt1) break;                                                  \
        }                                                                            \
    }                                                                                \
    float* mrg = (float*)(MEM + ((pg * 2 + (PHASE)) * 6400)) + lane * 25;            \
    if (hf) {                                                                        \
        _Pragma("unroll")                                                            \
        for (int dt = 0; dt < 4; ++dt)                                               \
            _Pragma("unroll")                                                        \
            for (int r = 0; r < 4; ++r) mrg[dt*4 + r] = O[dt][r];                    \
        _Pragma("unroll")                                                            \
        for (int r = 0; r < 4; ++r) { mrg[16 + r] = mrow[r]; mrg[20 + r] = lrow[r]; }\
    }                                                                                \
    __syncthreads();                                                                 \
    if (!hf) {                                                                       \
        _Pragma("unroll")                                                            \
        for (int r = 0; r < 4; ++r) {                                                \
            float mB = mrg[16 + r], lB = mrg[20 + r];                                \
            float ms = fmaxf(mrow[r], mB);                                           \
            float eA = __expf(mrow[r] - ms), eB = __expf(mB - ms);                   \
            float inv = 1.0f / (lrow[r] * eA + lB * eB);                             \
            int t = qbase + l4*4 + r;                                                \
            _Pragma("unroll")                                                        \
            for (int dt = 0; dt < 4; ++dt)                                           \
                outp[(b * 2048 + t) * 1024 + h * 64 + dt*16 + l15] =                 \
                    (O[dt][r] * eA + mrg[dt*4 + r] * eB) * inv;                      \
        }                                                                            \
    }                                                                                \
} while (0)

__global__ __launch_bounds__(256, 4) void attn(
        const short* __restrict__ Qb, const short* __restrict__ Kb,
        const short* __restrict__ Vt, const float* __restrict__ amask,
        float* __restrict__ outp) {
    __shared__ __align__(16) char MEM[4 * 6400 + 4 * 2304];  // merge regions + P-buffers

    const int tid = threadIdx.x, wv = tid >> 6, lane = tid & 63;
    const int l15 = lane & 15, l4 = lane >> 4;
    // XCD-chunked swizzle: 1024 blocks -> XCD x gets wids [x*128, x*128+127] (4 bh each)
    const int wid = ((blockIdx.x & 7) << 7) + (blockIdx.x >> 3);
    const int bh = wid >> 5;
    const int j  = wid & 31;
    const int pg = wv >> 1;                  // pair group within block
    const int hf = wv & 1;                   // kv half
    const int i  = 2 * j + pg;               // pair index 0..63
    const int b = bh >> 4, h = bh & 15;

    const short* Qp = Qb + bh * TT * HDD;
    const short* Kp = Kb + bh * TT * HDD;
    const short* Vp = Vt + bh * HDD * TT;
    const float* mp = amask + b * TT;
    short* pbw = (short*)(MEM + 4 * 6400 + wv * 2304);

    JOB(127 - i, 0);   // big tile of the pair
    JOB(i, 1);         // small tile
}

extern "C" void kernel_launch(void* const* d_in, const int* in_sizes, int n_in,
                              void* d_out, int out_size, void* d_ws, size_t ws_size,
                              hipStream_t stream) {
    const float* hidden = (const float*)d_in[0];
    const float* amask  = (const float*)d_in[1];
    const float* Wq = (const float*)d_in[2];
    const float* bq = (const float*)d_in[3];
    const float* Aq = (const float*)d_in[4];
    const float* Bq = (const float*)d_in[5];
    const float* Wk = (const float*)d_in[6];
    const float* bk = (const float*)d_in[7];
    const float* Wv = (const float*)d_in[8];
    const float* bv = (const float*)d_in[9];
    const float* Av = (const float*)d_in[10];
    const float* Bv = (const float*)d_in[11];
    float* outp = (float*)d_out;

    char* ws = (char*)d_ws;
    short* Xbf = (short*)(ws);                 // 8 MB  [4096][1024] bf16
    short* Wqe = (short*)(ws + (8 << 20));     // 2 MB
    short* Wke = (short*)(ws + (10 << 20));    // 2 MB
    short* Wve = (short*)(ws + (12 << 20));    // 2 MB
    short* Qb  = (short*)(ws + (14 << 20));    // 8 MB  [b][h][t][d]
    short* Kb  = (short*)(ws + (22 << 20));    // 8 MB  [b][h][t][d]
    short* Vtb = (short*)(ws + (30 << 20));    // 8 MB  [b][h][d][t]

    cvt_hidden<<<4096, 256, 0, stream>>>(hidden, Xbf);
    prep_w<<<4096, 256, 0, stream>>>(Wq, Aq, Bq, Wqe, 1);
    prep_w<<<4096, 256, 0, stream>>>(Wk, nullptr, nullptr, Wke, 0);
    prep_w<<<4096, 256, 0, stream>>>(Wv, Av, Bv, Wve, 1);
    proj_gemm<<<dim3(8, 32, 3), 256, 0, stream>>>(Xbf, Wqe, Wke, Wve, bq, bk, bv, Qb, Kb, Vtb);
    attn<<<1024, 256, 0, stream>>>(Qb, Kb, Vtb, amask, outp);
}

// Round 6
// 205.073 us; speedup vs baseline: 1.4836x; 1.4836x over previous
//
#include <hip/hip_runtime.h>
#include <hip/hip_bf16.h>

#define BB 2
#define TT 2048
#define DMM 1024
#define HH 16
#define HDD 64

typedef __attribute__((ext_vector_type(8))) short bf16x8;
typedef __attribute__((ext_vector_type(4))) short short4v;
typedef __attribute__((ext_vector_type(4))) float f32x4;

static __device__ __forceinline__ short f2bf(float f) {
    __hip_bfloat16 h = __float2bfloat16(f);
    return *reinterpret_cast<short*>(&h);
}

// ---- hidden f32 -> bf16 (4 elems/thread) ----
__global__ void cvt_hidden(const float* __restrict__ x, short* __restrict__ y) {
    int i = blockIdx.x * 256 + threadIdx.x;          // 1M threads, 4M elems
    float4 v = reinterpret_cast<const float4*>(x)[i];
    short4v o;
    o[0] = f2bf(v.x); o[1] = f2bf(v.y); o[2] = f2bf(v.z); o[3] = f2bf(v.w);
    reinterpret_cast<short4v*>(y)[i] = o;
}

// ---- W_eff = W + 2.0 * B@A  (or plain W), cast bf16 ----
__global__ void prep_w(const float* __restrict__ W, const float* __restrict__ A,
                       const float* __restrict__ Bm, short* __restrict__ outp, int lora) {
    int idx = blockIdx.x * 256 + threadIdx.x;        // 1M elems
    int n = idx >> 10, k = idx & 1023;
    float v = W[idx];
    if (lora) {
        float s = 0.f;
#pragma unroll
        for (int r = 0; r < 8; ++r) s += Bm[n * 8 + r] * A[r * 1024 + k];
        v += 2.0f * s;
    }
    outp[idx] = f2bf(v);
}

// ---- projection GEMM: C[m,n] = X[m,:] . W[n,:]  (both row-major, K contiguous) ----
// z = 0: Q (scale 0.125, layout [b][h][t][d]); z=1: K (same layout); z=2: V -> [b][h][d][t]
__global__ __launch_bounds__(256) void proj_gemm(
        const short* __restrict__ Xbf,
        const short* __restrict__ Wq, const short* __restrict__ Wk, const short* __restrict__ Wv,
        const float* __restrict__ bq, const float* __restrict__ bk, const float* __restrict__ bv,
        short* __restrict__ Qb, short* __restrict__ Kb, short* __restrict__ Vtb) {
    __shared__ __align__(16) char As[128 * 128];     // 128 rows x 64 bf16 (128B), swizzled
    __shared__ __align__(16) char Bs[128 * 128];

    const int mode = blockIdx.z;
    const short* Wbf = (mode == 0) ? Wq : (mode == 1) ? Wk : Wv;
    const float* bias = (mode == 0) ? bq : (mode == 1) ? bk : bv;
    short* outp = (mode == 0) ? Qb : (mode == 1) ? Kb : Vtb;
    const float scale = (mode == 0) ? 0.125f : 1.0f;  // HD^-0.5 folded into Q

    const int tid = threadIdx.x;
    const int wave = tid >> 6, lane = tid & 63;
    const int l15 = lane & 15, l4 = lane >> 4;
    const int m0 = blockIdx.y * 128, n0 = blockIdx.x * 128;
    const int wm = (wave >> 1) * 64, wn = (wave & 1) * 64;

    const int srow = tid >> 1;            // staging row 0..127
    const int scc = (tid & 1) * 4;        // 16B-chunk base (of 8 per row)

    f32x4 acc[4][4] = {};

    for (int k0 = 0; k0 < 1024; k0 += 64) {
        __syncthreads();
#pragma unroll
        for (int c = 0; c < 4; ++c) {
            int cc = scc + c;
            uint4 va = *reinterpret_cast<const uint4*>(Xbf + (m0 + srow) * 1024 + k0 + cc * 8);
            *reinterpret_cast<uint4*>(As + ((srow * 128 + cc * 16) ^ ((srow & 7) << 4))) = va;
            uint4 vb = *reinterpret_cast<const uint4*>(Wbf + (n0 + srow) * 1024 + k0 + cc * 8);
            *reinterpret_cast<uint4*>(Bs + ((srow * 128 + cc * 16) ^ ((srow & 7) << 4))) = vb;
        }
        __syncthreads();
#pragma unroll
        for (int kk = 0; kk < 2; ++kk) {
            const int colb = kk * 64 + l4 * 16;
            bf16x8 af[4], bfr[4];
#pragma unroll
            for (int mi = 0; mi < 4; ++mi) {
                int rowa = wm + mi * 16 + l15;
                af[mi] = *reinterpret_cast<const bf16x8*>(As + ((rowa * 128 + colb) ^ ((rowa & 7) << 4)));
                int rowb = wn + mi * 16 + l15;
                bfr[mi] = *reinterpret_cast<const bf16x8*>(Bs + ((rowb * 128 + colb) ^ ((rowb & 7) << 4)));
            }
#pragma unroll
            for (int mi = 0; mi < 4; ++mi)
#pragma unroll
                for (int ni = 0; ni < 4; ++ni)
                    acc[mi][ni] = __builtin_amdgcn_mfma_f32_16x16x32_bf16(af[mi], bfr[ni], acc[mi][ni], 0, 0, 0);
        }
    }

    // epilogue: C row = (l>>4)*4 + r, col = l&15
#pragma unroll
    for (int mi = 0; mi < 4; ++mi)
#pragma unroll
        for (int ni = 0; ni < 4; ++ni) {
            int gn = n0 + wn + ni * 16 + l15;
            float bv = bias[gn];
            int h = gn >> 6, d = gn & 63;
#pragma unroll
            for (int r = 0; r < 4; ++r) {
                int gm = m0 + wm + mi * 16 + l4 * 4 + r;
                int b = gm >> 11, t = gm & 2047;
                float v = (acc[mi][ni][r] + bv) * scale;
                int off;
                if (mode == 2) off = ((b * 16 + h) * 64 + d) * 2048 + t;     // V transposed
                else           off = ((b * 16 + h) * 2048 + t) * 64 + d;
                outp[off] = f2bf(v);
            }
        }
}

// ---- flash attention v4: interleaved pair, KVBLK=32 ----
// 512 blocks x 4 waves = 2048 waves. Wave (bh, i) processes BOTH q-tiles of the
// pair (127-i, i) INTERLEAVED over a shared K/V tile stream (tile i's kv range
// is a subset of tile 127-i's). Two independent QK->softmax->PV chains per
// iteration give 2x ILP on the latency-bound path; K/V loads amortized x2.
// No cross-wave merge, no launch_bounds cap (R5 spill lesson).

#define LOADK32(dst, kvb_) do {                                                      \
    int _kb = (kvb_);                                                                \
    _Pragma("unroll")                                                                \
    for (int _sl = 0; _sl < 2; ++_sl) {                                              \
        dst[_sl][0] = *reinterpret_cast<const bf16x8*>(Kp + (_kb + _sl*16 + l15)*64 + l4*8);      \
        dst[_sl][1] = *reinterpret_cast<const bf16x8*>(Kp + (_kb + _sl*16 + l15)*64 + 32 + l4*8); \
    }                                                                                \
} while (0)

// QK^T + online softmax for one 16-row q-tile against the current 32-key tile.
// Leaves exp'd P in the tile's LDS buffer (bf16), updates O-scale/m/l.
#define TILE_QKSM(QF0, QF1, OO, MR, LR, QB, PB) do {                                 \
    f32x4 ss0 = {}, ss1 = {};                                                        \
    ss0 = __builtin_amdgcn_mfma_f32_16x16x32_bf16(QF0, cur[0][0], ss0, 0, 0, 0);     \
    ss0 = __builtin_amdgcn_mfma_f32_16x16x32_bf16(QF1, cur[0][1], ss0, 0, 0, 0);     \
    ss1 = __builtin_amdgcn_mfma_f32_16x16x32_bf16(QF0, cur[1][0], ss1, 0, 0, 0);     \
    ss1 = __builtin_amdgcn_mfma_f32_16x16x32_bf16(QF1, cur[1][1], ss1, 0, 0, 0);     \
    float pr[2][4];                                                                  \
    if (kvb + 31 > (QB)) {                                                           \
        _Pragma("unroll")                                                            \
        for (int r = 0; r < 4; ++r) {                                                \
            float v0 = ss0[r] + mvs[0];                                              \
            if (kvb + l15 > (QB) + l4*4 + r) v0 = -1e30f;                            \
            pr[0][r] = v0;                                                           \
            float v1 = ss1[r] + mvs[1];                                              \
            if (kvb + 16 + l15 > (QB) + l4*4 + r) v1 = -1e30f;                       \
            pr[1][r] = v1;                                                           \
        }                                                                            \
    } else {                                                                         \
        _Pragma("unroll")                                                            \
        for (int r = 0; r < 4; ++r) { pr[0][r] = ss0[r] + mvs[0]; pr[1][r] = ss1[r] + mvs[1]; } \
    }                                                                                \
    float rmax[4];                                                                   \
    _Pragma("unroll")                                                                \
    for (int r = 0; r < 4; ++r) {                                                    \
        rmax[r] = fmaxf(pr[0][r], pr[1][r]);                                         \
        _Pragma("unroll")                                                            \
        for (int d = 1; d < 16; d <<= 1)                                             \
            rmax[r] = fmaxf(rmax[r], __shfl_xor(rmax[r], d, 16));                    \
    }                                                                                \
    float g = fmaxf(fmaxf(rmax[0]-MR[0], rmax[1]-MR[1]),                             \
                    fmaxf(rmax[2]-MR[2], rmax[3]-MR[3]));                            \
    if (!__all(g <= 8.0f)) {                                                         \
        _Pragma("unroll")                                                            \
        for (int r = 0; r < 4; ++r) {                                                \
            float mn = fmaxf(MR[r], rmax[r]);                                        \
            float al = __expf(MR[r] - mn);                                           \
            MR[r] = mn; LR[r] *= al;                                                 \
            _Pragma("unroll")                                                        \
            for (int dt = 0; dt < 4; ++dt) OO[dt][r] *= al;                          \
        }                                                                            \
    }                                                                                \
    _Pragma("unroll")                                                                \
    for (int r = 0; r < 4; ++r) { pr[0][r] = __expf(pr[0][r] - MR[r]); pr[1][r] = __expf(pr[1][r] - MR[r]); } \
    _Pragma("unroll")                                                                \
    for (int r = 0; r < 4; ++r) {                                                    \
        float ps = pr[0][r] + pr[1][r];                                              \
        _Pragma("unroll")                                                            \
        for (int d = 1; d < 16; d <<= 1) ps += __shfl_xor(ps, d, 16);                \
        LR[r] += ps;                                                                 \
    }                                                                                \
    _Pragma("unroll")                                                                \
    for (int r = 0; r < 4; ++r) {                                                    \
        (PB)[(l4*4 + r)*40 + l15]      = f2bf(pr[0][r]);                             \
        (PB)[(l4*4 + r)*40 + 16 + l15] = f2bf(pr[1][r]);                             \
    }                                                                                \
} while (0)

#define TILE_PV(OO, PB) do {                                                         \
    bf16x8 pf = *reinterpret_cast<const bf16x8*>((PB) + l15*40 + l4*8);              \
    _Pragma("unroll")                                                                \
    for (int dt = 0; dt < 4; ++dt)                                                   \
        OO[dt] = __builtin_amdgcn_mfma_f32_16x16x32_bf16(pf, vf[dt], OO[dt], 0, 0, 0); \
} while (0)

#define STEP(CUR, NXT, KT) do {                                                      \
    bf16x8 (*cur)[2] = CUR;                                                          \
    const int kvb = (KT) << 5;                                                       \
    LOADK32(NXT, kvb + 32);                                                          \
    bf16x8 vf[4];                                                                    \
    _Pragma("unroll")                                                                \
    for (int dt = 0; dt < 4; ++dt)                                                   \
        vf[dt] = *reinterpret_cast<const bf16x8*>(Vp + (dt*16 + l15)*2048 + kvb + l4*8); \
    float mvs[2];                                                                    \
    mvs[0] = mp[kvb + l15]; mvs[1] = mp[kvb + 16 + l15];                             \
    const bool doB = (KT) < nktB;                                                    \
    TILE_QKSM(qfA0, qfA1, OA, mA, lA, qbaseA, pbA);                                  \
    if (doB) TILE_QKSM(qfB0, qfB1, OB, mB, lB, qbaseB, pbB);                         \
    asm volatile("s_waitcnt lgkmcnt(0)" ::: "memory");                               \
    TILE_PV(OA, pbA);                                                                \
    if (doB) TILE_PV(OB, pbB);                                                       \
} while (0)

__global__ __launch_bounds__(256) void attn(
        const short* __restrict__ Qb, const short* __restrict__ Kb,
        const short* __restrict__ Vt, const float* __restrict__ amask,
        float* __restrict__ outp) {
    __shared__ __align__(16) short pb[4][2][16 * 40];  // per-wave A/B P buffers (80B row stride)

    const int tid = threadIdx.x, wv = tid >> 6, lane = tid & 63;
    const int l15 = lane & 15, l4 = lane >> 4;
    // XCD-chunked swizzle: 512 blocks, HW id x -> work id (x%8)*64 + x/8
    const int wid = ((blockIdx.x & 7) << 6) + (blockIdx.x >> 3);
    const int w = wid * 4 + wv;
    const int bh = w >> 6;                           // 32 (b,h) x 64 waves
    const int i = w & 63;                            // pair index
    const int b = bh >> 4, h = bh & 15;

    const short* Qp = Qb + bh * TT * HDD;
    const short* Kp = Kb + bh * TT * HDD;
    const short* Vp = Vt + bh * HDD * TT;
    const float* mp = amask + b * TT;
    short* pbA = &pb[wv][0][0];
    short* pbB = &pb[wv][1][0];

    const int qbaseA = (127 - i) << 4;               // big tile
    const int qbaseB = i << 4;                       // small tile (kv range subset of A's)

    bf16x8 qfA0 = *reinterpret_cast<const bf16x8*>(Qp + (qbaseA + l15) * 64 + l4 * 8);
    bf16x8 qfA1 = *reinterpret_cast<const bf16x8*>(Qp + (qbaseA + l15) * 64 + 32 + l4 * 8);
    bf16x8 qfB0 = *reinterpret_cast<const bf16x8*>(Qp + (qbaseB + l15) * 64 + l4 * 8);
    bf16x8 qfB1 = *reinterpret_cast<const bf16x8*>(Qp + (qbaseB + l15) * 64 + 32 + l4 * 8);

    f32x4 OA[4] = {}, OB[4] = {};
    float mA[4] = {-1e30f, -1e30f, -1e30f, -1e30f};
    float mB[4] = {-1e30f, -1e30f, -1e30f, -1e30f};
    float lA[4] = {0.f, 0.f, 0.f, 0.f};
    float lB[4] = {0.f, 0.f, 0.f, 0.f};

    const int nktA = (qbaseA + 47) >> 5;             // 32-wide kv tiles, causal bound
    const int nktB = (qbaseB + 47) >> 5;

    bf16x8 kfP[2][2], kfQ[2][2];
    LOADK32(kfP, 0);

    int kt = 0;
    while (1) {
        STEP(kfP, kfQ, kt);
        if (++kt >= nktA) break;
        STEP(kfQ, kfP, kt);
        if (++kt >= nktA) break;
    }

#pragma unroll
    for (int r = 0; r < 4; ++r) {
        float invA = 1.0f / lA[r], invB = 1.0f / lB[r];
        int tA = qbaseA + l4 * 4 + r, tB = qbaseB + l4 * 4 + r;
#pragma unroll
        for (int dt = 0; dt < 4; ++dt) {
            outp[(b * 2048 + tA) * 1024 + h * 64 + dt * 16 + l15] = OA[dt][r] * invA;
            outp[(b * 2048 + tB) * 1024 + h * 64 + dt * 16 + l15] = OB[dt][r] * invB;
        }
    }
}

extern "C" void kernel_launch(void* const* d_in, const int* in_sizes, int n_in,
                              void* d_out, int out_size, void* d_ws, size_t ws_size,
                              hipStream_t stream) {
    const float* hidden = (const float*)d_in[0];
    const float* amask  = (const float*)d_in[1];
    const float* Wq = (const float*)d_in[2];
    const float* bq = (const float*)d_in[3];
    const float* Aq = (const float*)d_in[4];
    const float* Bq = (const float*)d_in[5];
    const float* Wk = (const float*)d_in[6];
    const float* bk = (const float*)d_in[7];
    const float* Wv = (const float*)d_in[8];
    const float* bv = (const float*)d_in[9];
    const float* Av = (const float*)d_in[10];
    const float* Bv = (const float*)d_in[11];
    float* outp = (float*)d_out;

    char* ws = (char*)d_ws;
    short* Xbf = (short*)(ws);                 // 8 MB  [4096][1024] bf16
    short* Wqe = (short*)(ws + (8 << 20));     // 2 MB
    short* Wke = (short*)(ws + (10 << 20));    // 2 MB
    short* Wve = (short*)(ws + (12 << 20));    // 2 MB
    short* Qb  = (short*)(ws + (14 << 20));    // 8 MB  [b][h][t][d]
    short* Kb  = (short*)(ws + (22 << 20));    // 8 MB  [b][h][t][d]
    short* Vtb = (short*)(ws + (30 << 20));    // 8 MB  [b][h][d][t]

    cvt_hidden<<<4096, 256, 0, stream>>>(hidden, Xbf);
    prep_w<<<4096, 256, 0, stream>>>(Wq, Aq, Bq, Wqe, 1);
    prep_w<<<4096, 256, 0, stream>>>(Wk, nullptr, nullptr, Wke, 0);
    prep_w<<<4096, 256, 0, stream>>>(Wv, Av, Bv, Wve, 1);
    proj_gemm<<<dim3(8, 32, 3), 256, 0, stream>>>(Xbf, Wqe, Wke, Wve, bq, bk, bv, Qb, Kb, Vtb);
    attn<<<512, 256, 0, stream>>>(Qb, Kb, Vtb, amask, outp);
}